// Round 10
// baseline (495.946 us; speedup 1.0000x reference)
//
#include <hip/hip_runtime.h>
#include <hip/hip_cooperative_groups.h>

// GNN surrogate — cooperative single-kernel: distributed prep -> grid.sync ->
// strided batch loop running round-7's 5-stage barrier-free chain with NO
// hoisted loop-invariants (round 9's hoisting spilled ~40 KB/batch to scratch:
// FETCH 660 MB / WRITE 307 MB; all reloads here are L1-hot ws reads instead).
// Folds (exact): M_l = W2[l]@W1[l+1] (adj row-normalized -> biases commute
// through aggregation), lift absorbed into W1eff (K=3 pad 32),
// v[j]=mean_i adj[i,j], u=W2[2]@W_ro, cp=(b2[2]·W_ro)*sum(v)+b_ro.

namespace cg = cooperative_groups;

typedef _Float16 f16;
typedef __attribute__((ext_vector_type(8))) _Float16 half8;
typedef __attribute__((ext_vector_type(4))) _Float16 half4;
typedef __attribute__((ext_vector_type(2))) __fp16 fp16x2;   // cvt_pkrtz native
typedef __attribute__((ext_vector_type(4))) float f32x4;

namespace {
constexpr int N = 128, H = 32;
// ws byte layout
constexpr int WS_ADJF = 0;       // f16 [128][128] adj row-major        (32768 B)
constexpr int WS_WFB  = 32768;   // f16 [3][2][64][8] B-frag-ordered Meff (6144 B)
constexpr int WS_BIAS = 38912;   // f32 [3][32] folded biases            (384 B)
constexpr int WS_V    = 39424;   // f32 [128] v[j]=mean_i adj[i][j]      (512 B)
constexpr int WS_U    = 39936;   // f32 [32]  u[k]=sum_c W2[2][k][c]W_ro (128 B)
constexpr int WS_C    = 40064;   // f32 [1]
constexpr int TS = 152;  // bufT row stride f16 (304 B)
constexpr int PS = 40;   // bufP row stride f16 (80 B)
}

static __device__ __forceinline__ half4 pk4(float a, float b, float c, float d) {
  union { half4 v; fp16x2 h[2]; } u;
  u.h[0] = __builtin_amdgcn_cvt_pkrtz(a, b);
  u.h[1] = __builtin_amdgcn_cvt_pkrtz(c, d);
  return u.v;
}
static __device__ __forceinline__ half4 relu4(half4 v) {
  const half4 z = {};
  return __builtin_elementwise_max(v, z);
}

// ---- one batch, round-7 body verbatim: all weight/bias loads INSIDE ----
static __device__ __forceinline__ void batch_once(
    const float* __restrict__ x, const char* __restrict__ ws,
    float* __restrict__ out, f16* slab,
    int b, int lane, int lrow, int quad) {
  const f16* adjf  = (const f16*)(ws + WS_ADJF);
  const f16* wfb   = (const f16*)(ws + WS_WFB);
  const float* bia = (const float*)(ws + WS_BIAS);
  const float* v   = (const float*)(ws + WS_V);
  const float* u   = (const float*)(ws + WS_U);
  const float* cp  = (const float*)(ws + WS_C);
  const f32x4 zero = {0.f, 0.f, 0.f, 0.f};

  // ---- L0: T0 = relu(x·W1eff + b0) -> bufT[fout][node] ----
  {
    const half8 w0 = *(const half8*)(wfb + 0 * 1024 + 0 * 512 + lane * 8);
    const half8 w1 = *(const half8*)(wfb + 0 * 1024 + 1 * 512 + lane * 8);
    const float bb0 = bia[lrow], bb1 = bia[16 + lrow];
    const f32x4 bi0 = {bb0, bb0, bb0, bb0};
    const f32x4 bi1 = {bb1, bb1, bb1, bb1};
#pragma unroll
    for (int g = 0; g < 8; ++g) {
      half8 ax = {};
      if (quad == 0) {
        const float* xr = x + ((size_t)b * N + g * 16 + lrow) * 3;
        union { half8 v8; fp16x2 p[4]; } xa;
        xa.v8 = (half8){};
        xa.p[0] = __builtin_amdgcn_cvt_pkrtz(xr[0], xr[1]);
        xa.p[1] = __builtin_amdgcn_cvt_pkrtz(xr[2], 0.f);
        ax = xa.v8;
      }
      const f32x4 c0 = __builtin_amdgcn_mfma_f32_16x16x32_f16(ax, w0, bi0, 0, 0, 0);
      const f32x4 c1 = __builtin_amdgcn_mfma_f32_16x16x32_f16(ax, w1, bi1, 0, 0, 0);
      *(half4*)(slab + lrow * TS + g * 16 + quad * 4)        = relu4(pk4(c0[0], c0[1], c0[2], c0[3]));
      *(half4*)(slab + (16 + lrow) * TS + g * 16 + quad * 4) = relu4(pk4(c1[0], c1[1], c1[2], c1[3]));
    }
  }

  // ---- G0: P0^T=T0^T·adj^T -> bufP; L1: T1=relu(P0·M0+c0) -> bufT; G1 ----
#pragma unroll
  for (int l = 0; l < 2; ++l) {
    {
      half8 aT[2][4];
#pragma unroll
      for (int t = 0; t < 2; ++t)
#pragma unroll
        for (int kt = 0; kt < 4; ++kt)
          aT[t][kt] = *(const half8*)(slab + (t * 16 + lrow) * TS + kt * 32 + quad * 8);
#pragma unroll
      for (int g = 0; g < 8; ++g) {
        f32x4 a0 = zero, a1 = zero;
#pragma unroll
        for (int kt = 0; kt < 4; ++kt) {
          const half8 bf = *(const half8*)(adjf + (g * 16 + lrow) * N + kt * 32 + quad * 8);
          a0 = __builtin_amdgcn_mfma_f32_16x16x32_f16(aT[0][kt], bf, a0, 0, 0, 0);
          a1 = __builtin_amdgcn_mfma_f32_16x16x32_f16(aT[1][kt], bf, a1, 0, 0, 0);
        }
        f16* prow = slab + (g * 16 + lrow) * PS;
        *(half4*)(prow + quad * 4)      = pk4(a0[0], a0[1], a0[2], a0[3]);
        *(half4*)(prow + 16 + quad * 4) = pk4(a1[0], a1[1], a1[2], a1[3]);
      }
    }
    if (l == 1) break;
    {
      half8 af[8];
#pragma unroll
      for (int g = 0; g < 8; ++g)
        af[g] = *(const half8*)(slab + (g * 16 + lrow) * PS + quad * 8);
      const half8 w0 = *(const half8*)(wfb + 1 * 1024 + 0 * 512 + lane * 8);
      const half8 w1 = *(const half8*)(wfb + 1 * 1024 + 1 * 512 + lane * 8);
      const float bb0 = bia[H + lrow], bb1 = bia[H + 16 + lrow];
      const f32x4 bi0 = {bb0, bb0, bb0, bb0};
      const f32x4 bi1 = {bb1, bb1, bb1, bb1};
#pragma unroll
      for (int g = 0; g < 8; ++g) {
        const f32x4 c0 = __builtin_amdgcn_mfma_f32_16x16x32_f16(af[g], w0, bi0, 0, 0, 0);
        const f32x4 c1 = __builtin_amdgcn_mfma_f32_16x16x32_f16(af[g], w1, bi1, 0, 0, 0);
        *(half4*)(slab + lrow * TS + g * 16 + quad * 4)        = relu4(pk4(c0[0], c0[1], c0[2], c0[3]));
        *(half4*)(slab + (16 + lrow) * TS + g * 16 + quad * 4) = relu4(pk4(c1[0], c1[1], c1[2], c1[3]));
      }
    }
  }

  // ---- L2 + folded readout ----
  {
    const half8 w0 = *(const half8*)(wfb + 2 * 1024 + 0 * 512 + lane * 8);
    const half8 w1 = *(const half8*)(wfb + 2 * 1024 + 1 * 512 + lane * 8);
    const float bb0 = bia[2 * H + lrow], bb1 = bia[2 * H + 16 + lrow];
    const f32x4 bi0 = {bb0, bb0, bb0, bb0};
    const f32x4 bi1 = {bb1, bb1, bb1, bb1};
    const float u0 = u[lrow], u1 = u[16 + lrow];
    float partial = 0.f;
#pragma unroll
    for (int g = 0; g < 8; ++g) {
      const half8 af = *(const half8*)(slab + (g * 16 + lrow) * PS + quad * 8);
      const f32x4 c0 = __builtin_amdgcn_mfma_f32_16x16x32_f16(af, w0, bi0, 0, 0, 0);
      const f32x4 c1 = __builtin_amdgcn_mfma_f32_16x16x32_f16(af, w1, bi1, 0, 0, 0);
      const float4 vv = *(const float4*)(v + g * 16 + quad * 4);
      const float s0 = fmaxf(c0[0], 0.f) * vv.x + fmaxf(c0[1], 0.f) * vv.y +
                       fmaxf(c0[2], 0.f) * vv.z + fmaxf(c0[3], 0.f) * vv.w;
      const float s1 = fmaxf(c1[0], 0.f) * vv.x + fmaxf(c1[1], 0.f) * vv.y +
                       fmaxf(c1[2], 0.f) * vv.z + fmaxf(c1[3], 0.f) * vv.w;
      partial += s0 * u0 + s1 * u1;
    }
#pragma unroll
    for (int off = 32; off > 0; off >>= 1) partial += __shfl_down(partial, off, 64);
    if (lane == 0) out[b] = partial + cp[0];
  }
}

// ---- distributed prep (device fn used by coop phase 0 and fallback prep) ----
static __device__ void prep_phase(const float* __restrict__ adj,
                                  const float* __restrict__ W_lift,
                                  const float* __restrict__ b_lift,
                                  const float* __restrict__ W1,
                                  const float* __restrict__ b1,
                                  const float* __restrict__ W2,
                                  const float* __restrict__ b2,
                                  const float* __restrict__ W_ro,
                                  const float* __restrict__ b_ro,
                                  char* __restrict__ ws,
                                  int blk, int tid, float* lds_tmp) {
  f16* adjf  = (f16*)(ws + WS_ADJF);
  f16* wfb   = (f16*)(ws + WS_WFB);
  float* bia = (float*)(ws + WS_BIAS);
  float* v   = (float*)(ws + WS_V);
  float* u   = (float*)(ws + WS_U);
  float* cp  = (float*)(ws + WS_C);

  const int gid = blk * 256 + tid;
  if (gid < N * N) adjf[gid] = (f16)adj[gid];   // blocks 0..63

  if (blk == 64) {
    float* tmp  = lds_tmp;         // [3][32][32] fp32
    float* sred = tmp + 3 * H * H; // [128]
    for (int idx = tid; idx < 3 * H * H; idx += 256) {
      const int l = idx >> 10, rem = idx & 1023;
      const int k = rem >> 5, fo = rem & 31;
      float val = 0.f;
      if (l == 0) {
        if (k < 3) for (int c = 0; c < H; ++c) val += W_lift[k * H + c] * W1[c * H + fo];
      } else {
        const float* w2l = W2 + (l - 1) * H * H;
        const float* w1n = W1 + l * H * H;
        for (int c = 0; c < H; ++c) val += w2l[k * H + c] * w1n[c * H + fo];
      }
      tmp[idx] = val;
    }
    if (tid < N) {
      float s = 0.f;
      for (int i = 0; i < N; ++i) s += adj[i * N + tid];
      v[tid] = s * (1.0f / N);
      sred[tid] = s * (1.0f / N);
    }
    if (tid < H) {
      float s0 = b1[tid], s1 = b1[H + tid], s2 = b1[2 * H + tid];
      for (int c = 0; c < H; ++c) {
        s0 += b_lift[c] * W1[c * H + tid];
        s1 += b2[c] * W1[H * H + c * H + tid];
        s2 += b2[H + c] * W1[2 * H * H + c * H + tid];
      }
      bia[tid] = s0; bia[H + tid] = s1; bia[2 * H + tid] = s2;
      float su = 0.f;
      for (int c = 0; c < H; ++c) su += W2[2 * H * H + tid * H + c] * W_ro[c];
      u[tid] = su;
    }
    __syncthreads();
    for (int idx = tid; idx < 3 * 1024; idx += 256) {
      const int l = idx >> 10, rem = idx & 1023;
      const int t = rem >> 9, ln = (rem >> 3) & 63, j = rem & 7;
      const int q = ln >> 4, lr = ln & 15;
      wfb[idx] = (f16)tmp[l * 1024 + (q * 8 + j) * 32 + (t * 16 + lr)];
    }
    if (tid == 0) {
      float c2r = 0.f;
      for (int k = 0; k < H; ++k) c2r += b2[2 * H + k] * W_ro[k];
      float S = 0.f;
      for (int j = 0; j < N; ++j) S += sred[j];
      cp[0] = c2r * S + b_ro[0];
    }
  }
}

// ================= cooperative single-kernel path =================
__global__ __launch_bounds__(256, 4)
void gnn_coop(const float* __restrict__ x,
              const float* __restrict__ adj,
              const float* __restrict__ W_lift,
              const float* __restrict__ b_lift,
              const float* __restrict__ W1,
              const float* __restrict__ b1,
              const float* __restrict__ W2,
              const float* __restrict__ b2,
              const float* __restrict__ W_ro,
              const float* __restrict__ b_ro,
              char* __restrict__ ws,
              float* __restrict__ out,
              int nbatch) {
  __shared__ f16 smem[4][5120];

  const int tid  = threadIdx.x;
  const int blk  = blockIdx.x;
  const int wave = tid >> 6;
  const int lane = tid & 63;
  const int lrow = lane & 15;
  const int quad = lane >> 4;

  prep_phase(adj, W_lift, b_lift, W1, b1, W2, b2, W_ro, b_ro, ws,
             blk, tid, (float*)&smem[0][0]);
  cg::this_grid().sync();

  const int stride = (int)gridDim.x * 4;
  f16* slab = &smem[wave][0];
  for (int b = blk * 4 + wave; b < nbatch; b += stride)
    batch_once(x, (const char*)ws, out, slab, b, lane, lrow, quad);
}

// ================= fallback two-kernel path (round-7 equivalent) ==========
__global__ void prep(const float* __restrict__ adj,
                     const float* __restrict__ W_lift,
                     const float* __restrict__ b_lift,
                     const float* __restrict__ W1,
                     const float* __restrict__ b1,
                     const float* __restrict__ W2,
                     const float* __restrict__ b2,
                     const float* __restrict__ W_ro,
                     const float* __restrict__ b_ro,
                     char* __restrict__ ws) {
  __shared__ float tmp[3 * H * H + N];
  // fallback prep uses 65 blocks so prep_phase covers adj (0..63) + folds (64)
  prep_phase(adj, W_lift, b_lift, W1, b1, W2, b2, W_ro, b_ro, ws,
             (int)blockIdx.x, (int)threadIdx.x, tmp);
}

__global__ __launch_bounds__(256, 4)
void gnn_main(const float* __restrict__ x,
              const char* __restrict__ ws,
              float* __restrict__ out,
              int nbatch) {
  __shared__ f16 smem[4][5120];
  const int tid  = threadIdx.x;
  const int wave = tid >> 6;
  const int lane = tid & 63;
  const int b = (int)blockIdx.x * 4 + wave;
  if (b < nbatch)
    batch_once(x, ws, out, &smem[wave][0], b, lane, lane & 15, lane >> 4);
}

extern "C" void kernel_launch(void* const* d_in, const int* in_sizes, int n_in,
                              void* d_out, int out_size, void* d_ws, size_t ws_size,
                              hipStream_t stream) {
  const float* x      = (const float*)d_in[0];
  const float* adj    = (const float*)d_in[1];
  const float* W_lift = (const float*)d_in[2];
  const float* b_lift = (const float*)d_in[3];
  const float* W1     = (const float*)d_in[4];
  const float* b1     = (const float*)d_in[5];
  const float* W2     = (const float*)d_in[6];
  const float* b2     = (const float*)d_in[7];
  const float* W_ro   = (const float*)d_in[8];
  const float* b_ro   = (const float*)d_in[9];
  char* ws = (char*)d_ws;
  float* o = (float*)d_out;
  int nbatch = in_sizes[0] / (N * 3);   // 16384

  int maxb = 0;
  hipError_t oe = hipOccupancyMaxActiveBlocksPerMultiprocessor(
      &maxb, (const void*)gnn_coop, 256, 0);
  int grid = maxb * 256;               // 256 CUs on MI355X
  if (grid > nbatch / 4) grid = nbatch / 4;
  if (oe == hipSuccess && grid >= 65) {
    void* args[] = {(void*)&x, (void*)&adj, (void*)&W_lift, (void*)&b_lift,
                    (void*)&W1, (void*)&b1, (void*)&W2, (void*)&b2,
                    (void*)&W_ro, (void*)&b_ro, (void*)&ws, (void*)&o,
                    (void*)&nbatch};
    hipError_t le = hipLaunchCooperativeKernel((const void*)gnn_coop,
                                               dim3(grid), dim3(256),
                                               args, 0, stream);
    if (le == hipSuccess) return;
  }
  hipLaunchKernelGGL(prep, dim3(65), dim3(256), 0, stream,
                     adj, W_lift, b_lift, W1, b1, W2, b2, W_ro, b_ro, ws);
  hipLaunchKernelGGL(gnn_main, dim3(nbatch / 4), dim3(256), 0, stream,
                     x, (const char*)ws, o, nbatch);
}

// Round 11
// 226.224 us; speedup vs baseline: 2.1923x; 2.1923x over previous
//
#include <hip/hip_runtime.h>

// GNN surrogate — round-7 verified two-kernel structure; prep shrunk to ONE
// block (grid=1). Empirics: r1's grid-1 prep had a 6 us bench-vs-kernel gap;
// r2-r7's grid-8 prep had ~70 us regardless of content — prep grid size is
// the only correlating variable. Coop single-kernel (r8-r10) abandoned:
// unexplained ~700 MB/launch HBM traffic pathology.
// Folds (exact): M_l = W2[l]@W1[l+1] (adj row-normalized -> biases commute
// through aggregation), lift absorbed into W1eff (K=3 pad 32),
// v[j]=mean_i adj[i,j], u=W2[2]@W_ro, cp=(b2[2]·W_ro)*sum(v)+b_ro.
// Layout rule: state is always the MFMA A-operand; C-frag writes land
// contiguously in the transposed buffer = next stage's contiguous A-read.

typedef _Float16 f16;
typedef __attribute__((ext_vector_type(8))) _Float16 half8;
typedef __attribute__((ext_vector_type(4))) _Float16 half4;
typedef __attribute__((ext_vector_type(2))) __fp16 fp16x2;   // cvt_pkrtz native
typedef __attribute__((ext_vector_type(4))) float f32x4;

namespace {
constexpr int N = 128, H = 32;
// ws byte layout
constexpr int WS_ADJF = 0;       // f16 [128][128] adj row-major        (32768 B)
constexpr int WS_WFB  = 32768;   // f16 [3][2][64][8] B-frag-ordered Meff (6144 B)
constexpr int WS_BIAS = 38912;   // f32 [3][32] folded biases            (384 B)
constexpr int WS_V    = 39424;   // f32 [128] v[j]=mean_i adj[i][j]      (512 B)
constexpr int WS_U    = 39936;   // f32 [32]  u[k]=sum_c W2[2][k][c]W_ro (128 B)
constexpr int WS_C    = 40064;   // f32 [1]
constexpr int TS = 152;  // bufT row stride f16 (304 B)
constexpr int PS = 40;   // bufP row stride f16 (80 B)
}

static __device__ __forceinline__ half4 pk4(float a, float b, float c, float d) {
  union { half4 v; fp16x2 h[2]; } u;
  u.h[0] = __builtin_amdgcn_cvt_pkrtz(a, b);
  u.h[1] = __builtin_amdgcn_cvt_pkrtz(c, d);
  return u.v;
}
static __device__ __forceinline__ half4 relu4(half4 v) {
  const half4 z = {};
  return __builtin_elementwise_max(v, z);
}

// ---- single-block prep: adj->f16, folded weights/biases, v, u, cp ----
__global__ void prep(const float* __restrict__ adj,
                     const float* __restrict__ W_lift,
                     const float* __restrict__ b_lift,
                     const float* __restrict__ W1,
                     const float* __restrict__ b1,
                     const float* __restrict__ W2,
                     const float* __restrict__ b2,
                     const float* __restrict__ W_ro,
                     const float* __restrict__ b_ro,
                     char* __restrict__ ws) {
  const int tid = threadIdx.x;
  f16* adjf  = (f16*)(ws + WS_ADJF);
  f16* wfb   = (f16*)(ws + WS_WFB);
  float* bia = (float*)(ws + WS_BIAS);
  float* v   = (float*)(ws + WS_V);
  float* u   = (float*)(ws + WS_U);
  float* cp  = (float*)(ws + WS_C);

  // adj -> f16, vectorized: 16 float4 loads / 16 half8 stores per thread
  {
    const float4* a4 = (const float4*)adj;
#pragma unroll
    for (int r = 0; r < 8; ++r) {
      const int idx = r * 512 + tid * 2;           // float4 index (2 per thread per row-pass)
      const float4 p = a4[idx], q = a4[idx + 1];
      union { half8 v8; fp16x2 h[4]; } o;
      o.h[0] = __builtin_amdgcn_cvt_pkrtz(p.x, p.y);
      o.h[1] = __builtin_amdgcn_cvt_pkrtz(p.z, p.w);
      o.h[2] = __builtin_amdgcn_cvt_pkrtz(q.x, q.y);
      o.h[3] = __builtin_amdgcn_cvt_pkrtz(q.z, q.w);
      *(half8*)(adjf + idx * 4) = o.v8;
    }
  }

  __shared__ float tmp[3][H][H];
  __shared__ float sred[N];
  for (int idx = tid; idx < 3 * H * H; idx += 256) {
    const int l = idx >> 10, rem = idx & 1023;
    const int k = rem >> 5, fo = rem & 31;
    float val = 0.f;
    if (l == 0) {
      if (k < 3) for (int c = 0; c < H; ++c) val += W_lift[k * H + c] * W1[c * H + fo];
    } else {
      const float* w2l = W2 + (l - 1) * H * H;
      const float* w1n = W1 + l * H * H;
      for (int c = 0; c < H; ++c) val += w2l[k * H + c] * w1n[c * H + fo];
    }
    tmp[l][k][fo] = val;
  }
  if (tid < N) {
    float s = 0.f;
    for (int i = 0; i < N; ++i) s += adj[i * N + tid];
    v[tid] = s * (1.0f / N);
    sred[tid] = s * (1.0f / N);
  }
  if (tid < H) {
    float s0 = b1[tid], s1 = b1[H + tid], s2 = b1[2 * H + tid];
    for (int c = 0; c < H; ++c) {
      s0 += b_lift[c] * W1[c * H + tid];
      s1 += b2[c] * W1[H * H + c * H + tid];
      s2 += b2[H + c] * W1[2 * H * H + c * H + tid];
    }
    bia[tid] = s0; bia[H + tid] = s1; bia[2 * H + tid] = s2;
    float su = 0.f;
    for (int c = 0; c < H; ++c) su += W2[2 * H * H + tid * H + c] * W_ro[c];
    u[tid] = su;
  }
  __syncthreads();
  // B-frag order: wfb[l][t][lane=q*16+lr][j] = Meff_l[q*8+j][t*16+lr]
  for (int idx = tid; idx < 3 * 1024; idx += 256) {
    const int l = idx >> 10, rem = idx & 1023;
    const int t = rem >> 9, ln = (rem >> 3) & 63, j = rem & 7;
    const int q = ln >> 4, lr = ln & 15;
    wfb[idx] = (f16)tmp[l][q * 8 + j][t * 16 + lr];
  }
  if (tid == 0) {
    float c2r = 0.f;
    for (int k = 0; k < H; ++k) c2r += b2[2 * H + k] * W_ro[k];
    float S = 0.f;
    for (int j = 0; j < N; ++j) S += sred[j];
    cp[0] = c2r * S + b_ro[0];
  }
}

__global__ __launch_bounds__(256, 4)
void gnn_mfma(const float* __restrict__ x,
              const char* __restrict__ ws,
              float* __restrict__ out) {
  __shared__ f16 smem[4][5120];   // 4 x 10240 B wave-private slabs

  const f16* adjf  = (const f16*)(ws + WS_ADJF);
  const f16* wfb   = (const f16*)(ws + WS_WFB);
  const float* bia = (const float*)(ws + WS_BIAS);
  const float* v   = (const float*)(ws + WS_V);
  const float* u   = (const float*)(ws + WS_U);
  const float* cp  = (const float*)(ws + WS_C);

  const int tid  = threadIdx.x;
  const int wave = tid >> 6;
  const int lane = tid & 63;
  const int lrow = lane & 15;
  const int quad = lane >> 4;
  const int b    = blockIdx.x * 4 + wave;

  f16* slab = &smem[wave][0];
  const f32x4 zero = {0.f, 0.f, 0.f, 0.f};

  // ---- L0: T0 = relu(x·W1eff + b0) -> bufT[fout][node] ----
  {
    const half8 w0 = *(const half8*)(wfb + 0 * 1024 + 0 * 512 + lane * 8);
    const half8 w1 = *(const half8*)(wfb + 0 * 1024 + 1 * 512 + lane * 8);
    const float bb0 = bia[lrow], bb1 = bia[16 + lrow];
    const f32x4 bi0 = {bb0, bb0, bb0, bb0};
    const f32x4 bi1 = {bb1, bb1, bb1, bb1};
#pragma unroll
    for (int g = 0; g < 8; ++g) {
      half8 ax = {};
      if (quad == 0) {
        const float* xr = x + ((size_t)b * N + g * 16 + lrow) * 3;
        union { half8 v8; fp16x2 p[4]; } xa;
        xa.v8 = (half8){};
        xa.p[0] = __builtin_amdgcn_cvt_pkrtz(xr[0], xr[1]);
        xa.p[1] = __builtin_amdgcn_cvt_pkrtz(xr[2], 0.f);
        ax = xa.v8;
      }
      const f32x4 c0 = __builtin_amdgcn_mfma_f32_16x16x32_f16(ax, w0, bi0, 0, 0, 0);
      const f32x4 c1 = __builtin_amdgcn_mfma_f32_16x16x32_f16(ax, w1, bi1, 0, 0, 0);
      *(half4*)(slab + lrow * TS + g * 16 + quad * 4)        = relu4(pk4(c0[0], c0[1], c0[2], c0[3]));
      *(half4*)(slab + (16 + lrow) * TS + g * 16 + quad * 4) = relu4(pk4(c1[0], c1[1], c1[2], c1[3]));
    }
  }

  // ---- G0: P0^T=T0^T·adj^T -> bufP; L1: T1=relu(P0·M0+c0) -> bufT; G1 ----
#pragma unroll
  for (int l = 0; l < 2; ++l) {
    {
      half8 aT[2][4];
#pragma unroll
      for (int t = 0; t < 2; ++t)
#pragma unroll
        for (int kt = 0; kt < 4; ++kt)
          aT[t][kt] = *(const half8*)(slab + (t * 16 + lrow) * TS + kt * 32 + quad * 8);
#pragma unroll
      for (int g = 0; g < 8; ++g) {
        f32x4 a0 = zero, a1 = zero;
#pragma unroll
        for (int kt = 0; kt < 4; ++kt) {
          const half8 bf = *(const half8*)(adjf + (g * 16 + lrow) * N + kt * 32 + quad * 8);
          a0 = __builtin_amdgcn_mfma_f32_16x16x32_f16(aT[0][kt], bf, a0, 0, 0, 0);
          a1 = __builtin_amdgcn_mfma_f32_16x16x32_f16(aT[1][kt], bf, a1, 0, 0, 0);
        }
        f16* prow = slab + (g * 16 + lrow) * PS;
        *(half4*)(prow + quad * 4)      = pk4(a0[0], a0[1], a0[2], a0[3]);
        *(half4*)(prow + 16 + quad * 4) = pk4(a1[0], a1[1], a1[2], a1[3]);
      }
    }
    if (l == 1) break;
    {
      half8 af[8];
#pragma unroll
      for (int g = 0; g < 8; ++g)
        af[g] = *(const half8*)(slab + (g * 16 + lrow) * PS + quad * 8);
      const half8 w0 = *(const half8*)(wfb + 1 * 1024 + 0 * 512 + lane * 8);
      const half8 w1 = *(const half8*)(wfb + 1 * 1024 + 1 * 512 + lane * 8);
      const float bb0 = bia[H + lrow], bb1 = bia[H + 16 + lrow];
      const f32x4 bi0 = {bb0, bb0, bb0, bb0};
      const f32x4 bi1 = {bb1, bb1, bb1, bb1};
#pragma unroll
      for (int g = 0; g < 8; ++g) {
        const f32x4 c0 = __builtin_amdgcn_mfma_f32_16x16x32_f16(af[g], w0, bi0, 0, 0, 0);
        const f32x4 c1 = __builtin_amdgcn_mfma_f32_16x16x32_f16(af[g], w1, bi1, 0, 0, 0);
        *(half4*)(slab + lrow * TS + g * 16 + quad * 4)        = relu4(pk4(c0[0], c0[1], c0[2], c0[3]));
        *(half4*)(slab + (16 + lrow) * TS + g * 16 + quad * 4) = relu4(pk4(c1[0], c1[1], c1[2], c1[3]));
      }
    }
  }

  // ---- L2 + folded readout: out = sum relu(P1·M1 + c1)[n][f]·v[n]·u[f] + cp
  {
    const half8 w0 = *(const half8*)(wfb + 2 * 1024 + 0 * 512 + lane * 8);
    const half8 w1 = *(const half8*)(wfb + 2 * 1024 + 1 * 512 + lane * 8);
    const float bb0 = bia[2 * H + lrow], bb1 = bia[2 * H + 16 + lrow];
    const f32x4 bi0 = {bb0, bb0, bb0, bb0};
    const f32x4 bi1 = {bb1, bb1, bb1, bb1};
    const float u0 = u[lrow], u1 = u[16 + lrow];
    float partial = 0.f;
#pragma unroll
    for (int g = 0; g < 8; ++g) {
      const half8 af = *(const half8*)(slab + (g * 16 + lrow) * PS + quad * 8);
      const f32x4 c0 = __builtin_amdgcn_mfma_f32_16x16x32_f16(af, w0, bi0, 0, 0, 0);
      const f32x4 c1 = __builtin_amdgcn_mfma_f32_16x16x32_f16(af, w1, bi1, 0, 0, 0);
      const float4 vv = *(const float4*)(v + g * 16 + quad * 4);
      const float s0 = fmaxf(c0[0], 0.f) * vv.x + fmaxf(c0[1], 0.f) * vv.y +
                       fmaxf(c0[2], 0.f) * vv.z + fmaxf(c0[3], 0.f) * vv.w;
      const float s1 = fmaxf(c1[0], 0.f) * vv.x + fmaxf(c1[1], 0.f) * vv.y +
                       fmaxf(c1[2], 0.f) * vv.z + fmaxf(c1[3], 0.f) * vv.w;
      partial += s0 * u0 + s1 * u1;
    }
#pragma unroll
    for (int off = 32; off > 0; off >>= 1) partial += __shfl_down(partial, off, 64);
    if (lane == 0) out[b] = partial + cp[0];
  }
}

extern "C" void kernel_launch(void* const* d_in, const int* in_sizes, int n_in,
                              void* d_out, int out_size, void* d_ws, size_t ws_size,
                              hipStream_t stream) {
  const float* x      = (const float*)d_in[0];
  const float* adj    = (const float*)d_in[1];
  const float* W_lift = (const float*)d_in[2];
  const float* b_lift = (const float*)d_in[3];
  const float* W1     = (const float*)d_in[4];
  const float* b1     = (const float*)d_in[5];
  const float* W2     = (const float*)d_in[6];
  const float* b2     = (const float*)d_in[7];
  const float* W_ro   = (const float*)d_in[8];
  const float* b_ro   = (const float*)d_in[9];
  char* ws = (char*)d_ws;
  float* o = (float*)d_out;

  const int B = in_sizes[0] / (N * 3);   // 16384
  hipLaunchKernelGGL(prep, dim3(1), dim3(256), 0, stream,
                     adj, W_lift, b_lift, W1, b1, W2, b2, W_ro, b_ro, ws);
  hipLaunchKernelGGL(gnn_mfma, dim3(B / 4), dim3(256), 0, stream,
                     x, (const char*)ws, o);
}

// Round 12
// 187.690 us; speedup vs baseline: 2.6424x; 1.2053x over previous
//
#include <hip/hip_runtime.h>

// GNN surrogate — f16 MFMA, TWO batches per wave (ILP), barrier-free.
// Wave owns 2 private slabs (9728 B each); stages interleaved A/B so one
// batch's MFMAs issue while the other's LDS/L2 chain drains. adjf B-frags
// and weights load once per pair. bufP stride 36 (b64 reads, conflict-free
// bank bases). Block = 128 thr (2 waves), 38912 B LDS -> 4 blocks/CU.
// Folds (exact): M_l = W2[l]@W1[l+1] (adj row-normalized -> biases commute
// through aggregation), lift absorbed into W1eff (K=3 pad 32),
// v[j]=mean_i adj[i,j], u=W2[2]@W_ro, cp=(b2[2]·W_ro)*sum(v)+b_ro.

typedef _Float16 f16;
typedef __attribute__((ext_vector_type(8))) _Float16 half8;
typedef __attribute__((ext_vector_type(4))) _Float16 half4;
typedef __attribute__((ext_vector_type(2))) __fp16 fp16x2;   // cvt_pkrtz native
typedef __attribute__((ext_vector_type(4))) float f32x4;

namespace {
constexpr int N = 128, H = 32;
// ws byte layout
constexpr int WS_ADJF = 0;       // f16 [128][128] adj row-major        (32768 B)
constexpr int WS_WFB  = 32768;   // f16 [3][2][64][8] B-frag-ordered Meff (6144 B)
constexpr int WS_BIAS = 38912;   // f32 [3][32] folded biases            (384 B)
constexpr int WS_V    = 39424;   // f32 [128] v[j]=mean_i adj[i][j]      (512 B)
constexpr int WS_U    = 39936;   // f32 [32]  u[k]=sum_c W2[2][k][c]W_ro (128 B)
constexpr int WS_C    = 40064;   // f32 [1]
constexpr int TS = 152;  // bufT row stride f16 (304 B; 76w step ≡12 mod 32: 2-way max)
constexpr int PS = 36;   // bufP row stride f16 (72 B; 18w step: 16 distinct banks)
constexpr int SLAB = 4864;       // f16 per slab = 9728 B (= 32*TS; bufP 4608 fits)
}

static __device__ __forceinline__ half4 pk4(float a, float b, float c, float d) {
  union { half4 v; fp16x2 h[2]; } u;
  u.h[0] = __builtin_amdgcn_cvt_pkrtz(a, b);
  u.h[1] = __builtin_amdgcn_cvt_pkrtz(c, d);
  return u.v;
}
static __device__ __forceinline__ half4 relu4(half4 v) {
  const half4 z = {};
  return __builtin_elementwise_max(v, z);
}
// bufP half8 read as 2x b64 (rows are 8B-aligned, not 16B)
static __device__ __forceinline__ half8 ldp(const f16* slab, int row, int quad) {
  union { half8 v; half4 h[2]; } u;
  u.h[0] = *(const half4*)(slab + row * PS + quad * 8);
  u.h[1] = *(const half4*)(slab + row * PS + quad * 8 + 4);
  return u.v;
}

// ---- single-block prep: adj->f16, folded weights/biases, v, u, cp ----
__global__ void prep(const float* __restrict__ adj,
                     const float* __restrict__ W_lift,
                     const float* __restrict__ b_lift,
                     const float* __restrict__ W1,
                     const float* __restrict__ b1,
                     const float* __restrict__ W2,
                     const float* __restrict__ b2,
                     const float* __restrict__ W_ro,
                     const float* __restrict__ b_ro,
                     char* __restrict__ ws) {
  const int tid = threadIdx.x;
  f16* adjf  = (f16*)(ws + WS_ADJF);
  f16* wfb   = (f16*)(ws + WS_WFB);
  float* bia = (float*)(ws + WS_BIAS);
  float* v   = (float*)(ws + WS_V);
  float* u   = (float*)(ws + WS_U);
  float* cp  = (float*)(ws + WS_C);

  {
    const float4* a4 = (const float4*)adj;
#pragma unroll
    for (int r = 0; r < 8; ++r) {
      const int idx = r * 512 + tid * 2;
      const float4 p = a4[idx], q = a4[idx + 1];
      union { half8 v8; fp16x2 h[4]; } o;
      o.h[0] = __builtin_amdgcn_cvt_pkrtz(p.x, p.y);
      o.h[1] = __builtin_amdgcn_cvt_pkrtz(p.z, p.w);
      o.h[2] = __builtin_amdgcn_cvt_pkrtz(q.x, q.y);
      o.h[3] = __builtin_amdgcn_cvt_pkrtz(q.z, q.w);
      *(half8*)(adjf + idx * 4) = o.v8;
    }
  }

  __shared__ float tmp[3][H][H];
  __shared__ float sred[N];
  for (int idx = tid; idx < 3 * H * H; idx += 256) {
    const int l = idx >> 10, rem = idx & 1023;
    const int k = rem >> 5, fo = rem & 31;
    float val = 0.f;
    if (l == 0) {
      if (k < 3) for (int c = 0; c < H; ++c) val += W_lift[k * H + c] * W1[c * H + fo];
    } else {
      const float* w2l = W2 + (l - 1) * H * H;
      const float* w1n = W1 + l * H * H;
      for (int c = 0; c < H; ++c) val += w2l[k * H + c] * w1n[c * H + fo];
    }
    tmp[l][k][fo] = val;
  }
  if (tid < N) {
    float s = 0.f;
    for (int i = 0; i < N; ++i) s += adj[i * N + tid];
    v[tid] = s * (1.0f / N);
    sred[tid] = s * (1.0f / N);
  }
  if (tid < H) {
    float s0 = b1[tid], s1 = b1[H + tid], s2 = b1[2 * H + tid];
    for (int c = 0; c < H; ++c) {
      s0 += b_lift[c] * W1[c * H + tid];
      s1 += b2[c] * W1[H * H + c * H + tid];
      s2 += b2[H + c] * W1[2 * H * H + c * H + tid];
    }
    bia[tid] = s0; bia[H + tid] = s1; bia[2 * H + tid] = s2;
    float su = 0.f;
    for (int c = 0; c < H; ++c) su += W2[2 * H * H + tid * H + c] * W_ro[c];
    u[tid] = su;
  }
  __syncthreads();
  for (int idx = tid; idx < 3 * 1024; idx += 256) {
    const int l = idx >> 10, rem = idx & 1023;
    const int t = rem >> 9, ln = (rem >> 3) & 63, j = rem & 7;
    const int q = ln >> 4, lr = ln & 15;
    wfb[idx] = (f16)tmp[l][q * 8 + j][t * 16 + lr];
  }
  if (tid == 0) {
    float c2r = 0.f;
    for (int k = 0; k < H; ++k) c2r += b2[2 * H + k] * W_ro[k];
    float S = 0.f;
    for (int j = 0; j < N; ++j) S += sred[j];
    cp[0] = c2r * S + b_ro[0];
  }
}

__global__ __launch_bounds__(128, 2)
void gnn_mfma(const float* __restrict__ x,
              const char* __restrict__ ws,
              float* __restrict__ out) {
  __shared__ f16 smem[4][SLAB];   // (2 waves)x(2 batches) slabs = 38912 B

  const f16* adjf  = (const f16*)(ws + WS_ADJF);
  const f16* wfb   = (const f16*)(ws + WS_WFB);
  const float* bia = (const float*)(ws + WS_BIAS);
  const float* v   = (const float*)(ws + WS_V);
  const float* u   = (const float*)(ws + WS_U);
  const float* cp  = (const float*)(ws + WS_C);

  const int tid  = threadIdx.x;
  const int wave = tid >> 6;
  const int lane = tid & 63;
  const int lrow = lane & 15;
  const int quad = lane >> 4;
  const int b0   = blockIdx.x * 4 + wave * 2;   // this wave: batches b0, b0+1

  f16* sA = &smem[wave * 2 + 0][0];
  f16* sB = &smem[wave * 2 + 1][0];
  const f32x4 zero = {0.f, 0.f, 0.f, 0.f};

  // ---- L0: T = relu(x·W1eff + b0) for both batches -> bufT[fout][node] ----
  {
    const half8 w0 = *(const half8*)(wfb + 0 * 1024 + 0 * 512 + lane * 8);
    const half8 w1 = *(const half8*)(wfb + 0 * 1024 + 1 * 512 + lane * 8);
    const float bb0 = bia[lrow], bb1 = bia[16 + lrow];
    const f32x4 bi0 = {bb0, bb0, bb0, bb0};
    const f32x4 bi1 = {bb1, bb1, bb1, bb1};
#pragma unroll
    for (int g = 0; g < 8; ++g) {
#pragma unroll
      for (int ab = 0; ab < 2; ++ab) {
        f16* slab = ab ? sB : sA;
        half8 ax = {};
        if (quad == 0) {
          const float* xr = x + ((size_t)(b0 + ab) * N + g * 16 + lrow) * 3;
          union { half8 v8; fp16x2 p[4]; } xa;
          xa.v8 = (half8){};
          xa.p[0] = __builtin_amdgcn_cvt_pkrtz(xr[0], xr[1]);
          xa.p[1] = __builtin_amdgcn_cvt_pkrtz(xr[2], 0.f);
          ax = xa.v8;
        }
        const f32x4 c0 = __builtin_amdgcn_mfma_f32_16x16x32_f16(ax, w0, bi0, 0, 0, 0);
        const f32x4 c1 = __builtin_amdgcn_mfma_f32_16x16x32_f16(ax, w1, bi1, 0, 0, 0);
        *(half4*)(slab + lrow * TS + g * 16 + quad * 4)        = relu4(pk4(c0[0], c0[1], c0[2], c0[3]));
        *(half4*)(slab + (16 + lrow) * TS + g * 16 + quad * 4) = relu4(pk4(c1[0], c1[1], c1[2], c1[3]));
      }
    }
  }

  // ---- G/L alternation: G0 -> L1 -> G1 ----
#pragma unroll
  for (int l = 0; l < 2; ++l) {
    // G: P^T = T^T·adj^T for both batches; adjf B-frag loaded ONCE per (g,kt)
    {
      half8 aTA[2][4], aTB[2][4];
#pragma unroll
      for (int t = 0; t < 2; ++t)
#pragma unroll
        for (int kt = 0; kt < 4; ++kt) {
          aTA[t][kt] = *(const half8*)(sA + (t * 16 + lrow) * TS + kt * 32 + quad * 8);
          aTB[t][kt] = *(const half8*)(sB + (t * 16 + lrow) * TS + kt * 32 + quad * 8);
        }
#pragma unroll
      for (int g = 0; g < 8; ++g) {
        f32x4 a0 = zero, a1 = zero, b0v = zero, b1v = zero;
#pragma unroll
        for (int kt = 0; kt < 4; ++kt) {
          const half8 bf = *(const half8*)(adjf + (g * 16 + lrow) * N + kt * 32 + quad * 8);
          a0  = __builtin_amdgcn_mfma_f32_16x16x32_f16(aTA[0][kt], bf, a0, 0, 0, 0);
          a1  = __builtin_amdgcn_mfma_f32_16x16x32_f16(aTA[1][kt], bf, a1, 0, 0, 0);
          b0v = __builtin_amdgcn_mfma_f32_16x16x32_f16(aTB[0][kt], bf, b0v, 0, 0, 0);
          b1v = __builtin_amdgcn_mfma_f32_16x16x32_f16(aTB[1][kt], bf, b1v, 0, 0, 0);
        }
        f16* pA = sA + (g * 16 + lrow) * PS;
        f16* pB = sB + (g * 16 + lrow) * PS;
        *(half4*)(pA + quad * 4)      = pk4(a0[0], a0[1], a0[2], a0[3]);
        *(half4*)(pA + 16 + quad * 4) = pk4(a1[0], a1[1], a1[2], a1[3]);
        *(half4*)(pB + quad * 4)      = pk4(b0v[0], b0v[1], b0v[2], b0v[3]);
        *(half4*)(pB + 16 + quad * 4) = pk4(b1v[0], b1v[1], b1v[2], b1v[3]);
      }
    }
    if (l == 1) break;

    // L1: T1 = relu(P·M0 + c0); preload ALL af (bufP) before bufT overwrites
    {
      half8 afA[8], afB[8];
#pragma unroll
      for (int g = 0; g < 8; ++g) {
        afA[g] = ldp(sA, g * 16 + lrow, quad);
        afB[g] = ldp(sB, g * 16 + lrow, quad);
      }
      const half8 w0 = *(const half8*)(wfb + 1 * 1024 + 0 * 512 + lane * 8);
      const half8 w1 = *(const half8*)(wfb + 1 * 1024 + 1 * 512 + lane * 8);
      const float bb0 = bia[H + lrow], bb1 = bia[H + 16 + lrow];
      const f32x4 bi0 = {bb0, bb0, bb0, bb0};
      const f32x4 bi1 = {bb1, bb1, bb1, bb1};
#pragma unroll
      for (int g = 0; g < 8; ++g) {
        const f32x4 cA0 = __builtin_amdgcn_mfma_f32_16x16x32_f16(afA[g], w0, bi0, 0, 0, 0);
        const f32x4 cA1 = __builtin_amdgcn_mfma_f32_16x16x32_f16(afA[g], w1, bi1, 0, 0, 0);
        const f32x4 cB0 = __builtin_amdgcn_mfma_f32_16x16x32_f16(afB[g], w0, bi0, 0, 0, 0);
        const f32x4 cB1 = __builtin_amdgcn_mfma_f32_16x16x32_f16(afB[g], w1, bi1, 0, 0, 0);
        *(half4*)(sA + lrow * TS + g * 16 + quad * 4)        = relu4(pk4(cA0[0], cA0[1], cA0[2], cA0[3]));
        *(half4*)(sA + (16 + lrow) * TS + g * 16 + quad * 4) = relu4(pk4(cA1[0], cA1[1], cA1[2], cA1[3]));
        *(half4*)(sB + lrow * TS + g * 16 + quad * 4)        = relu4(pk4(cB0[0], cB0[1], cB0[2], cB0[3]));
        *(half4*)(sB + (16 + lrow) * TS + g * 16 + quad * 4) = relu4(pk4(cB1[0], cB1[1], cB1[2], cB1[3]));
      }
    }
  }

  // ---- L2 + folded readout for both batches ----
  {
    const half8 w0 = *(const half8*)(wfb + 2 * 1024 + 0 * 512 + lane * 8);
    const half8 w1 = *(const half8*)(wfb + 2 * 1024 + 1 * 512 + lane * 8);
    const float bb0 = bia[2 * H + lrow], bb1 = bia[2 * H + 16 + lrow];
    const f32x4 bi0 = {bb0, bb0, bb0, bb0};
    const f32x4 bi1 = {bb1, bb1, bb1, bb1};
    const float u0 = u[lrow], u1 = u[16 + lrow];
    float pA = 0.f, pB = 0.f;
#pragma unroll
    for (int g = 0; g < 8; ++g) {
      const half8 afA = ldp(sA, g * 16 + lrow, quad);
      const half8 afB = ldp(sB, g * 16 + lrow, quad);
      const f32x4 cA0 = __builtin_amdgcn_mfma_f32_16x16x32_f16(afA, w0, bi0, 0, 0, 0);
      const f32x4 cA1 = __builtin_amdgcn_mfma_f32_16x16x32_f16(afA, w1, bi1, 0, 0, 0);
      const f32x4 cB0 = __builtin_amdgcn_mfma_f32_16x16x32_f16(afB, w0, bi0, 0, 0, 0);
      const f32x4 cB1 = __builtin_amdgcn_mfma_f32_16x16x32_f16(afB, w1, bi1, 0, 0, 0);
      const float4 vv = *(const float4*)(v + g * 16 + quad * 4);
      pA += (fmaxf(cA0[0], 0.f) * vv.x + fmaxf(cA0[1], 0.f) * vv.y +
             fmaxf(cA0[2], 0.f) * vv.z + fmaxf(cA0[3], 0.f) * vv.w) * u0 +
            (fmaxf(cA1[0], 0.f) * vv.x + fmaxf(cA1[1], 0.f) * vv.y +
             fmaxf(cA1[2], 0.f) * vv.z + fmaxf(cA1[3], 0.f) * vv.w) * u1;
      pB += (fmaxf(cB0[0], 0.f) * vv.x + fmaxf(cB0[1], 0.f) * vv.y +
             fmaxf(cB0[2], 0.f) * vv.z + fmaxf(cB0[3], 0.f) * vv.w) * u0 +
            (fmaxf(cB1[0], 0.f) * vv.x + fmaxf(cB1[1], 0.f) * vv.y +
             fmaxf(cB1[2], 0.f) * vv.z + fmaxf(cB1[3], 0.f) * vv.w) * u1;
    }
#pragma unroll
    for (int off = 32; off > 0; off >>= 1) {
      pA += __shfl_down(pA, off, 64);
      pB += __shfl_down(pB, off, 64);
    }
    if (lane == 0) {
      const float c0 = cp[0];
      out[b0]     = pA + c0;
      out[b0 + 1] = pB + c0;
    }
  }
}

extern "C" void kernel_launch(void* const* d_in, const int* in_sizes, int n_in,
                              void* d_out, int out_size, void* d_ws, size_t ws_size,
                              hipStream_t stream) {
  const float* x      = (const float*)d_in[0];
  const float* adj    = (const float*)d_in[1];
  const float* W_lift = (const float*)d_in[2];
  const float* b_lift = (const float*)d_in[3];
  const float* W1     = (const float*)d_in[4];
  const float* b1     = (const float*)d_in[5];
  const float* W2     = (const float*)d_in[6];
  const float* b2     = (const float*)d_in[7];
  const float* W_ro   = (const float*)d_in[8];
  const float* b_ro   = (const float*)d_in[9];
  char* ws = (char*)d_ws;
  float* o = (float*)d_out;

  const int B = in_sizes[0] / (N * 3);   // 16384
  hipLaunchKernelGGL(prep, dim3(1), dim3(256), 0, stream,
                     adj, W_lift, b_lift, W1, b1, W2, b2, W_ro, b_ro, ws);
  hipLaunchKernelGGL(gnn_mfma, dim3(B / 4), dim3(128), 0, stream,
                     x, (const char*)ws, o);
}